// Round 1
// baseline (201.761 us; speedup 1.0000x reference)
//
#include <hip/hip_runtime.h>

namespace {
constexpr int Bn = 8, Cn = 256, Hn = 64, Wn = 64;
constexpr int Kk = 5, PAD = 2, KMC = 100;  // KMC = UP^2 * K^2
}

// grid (H, B), block 256 = 4 waves; lane = w (0..63); wave wv handles 4
// channels per channel-group iteration.
__global__ __launch_bounds__(256, 2) void carafe_fwd(
    const float* __restrict__ x,    // [B, C, H, W]
    const float* __restrict__ km,   // [B, 100, H, W]
    float* __restrict__ out)        // [B, C, 2H, 2W]
{
    const int h   = blockIdx.x;
    const int b   = blockIdx.y;
    const int tid = threadIdx.x;
    const int wv  = tid >> 6;
    const int w   = tid & 63;

    // wave-private staging tile, channel-interleaved for aligned b128 taps
    __shared__ __align__(16) float xs[4][Kk][68][4];

    // zero horizontal halo columns (padded cols 0,1,66,67) once per wave
    if (w < Kk * 4) {
        const int r  = w >> 2;
        const int hc = w & 3;
        const int wp = (hc < 2) ? hc : 64 + hc;
        #pragma unroll
        for (int k = 0; k < 4; ++k) xs[wv][r][wp][k] = 0.0f;
    }

    // per-pixel reassembly weights -> 100 registers (reused over all 256 ch)
    float wreg[KMC];
    {
        const float* kmp = km + (((size_t)b * KMC) * Hn + h) * Wn + w;
        #pragma unroll
        for (int ch = 0; ch < KMC; ++ch)
            wreg[ch] = kmp[(size_t)ch * (Hn * Wn)];
    }

    const float* xb = x + (size_t)b * Cn * Hn * Wn;
    float* ob       = out + (size_t)b * Cn * (2 * Hn) * (2 * Wn);

    for (int cb = 0; cb < Cn / 16; ++cb) {
        const int c0 = cb * 16 + wv * 4;

        // stage 4 channels x 5 rows (rows h-2..h+2, zero-padded) into LDS
        #pragma unroll
        for (int r = 0; r < Kk; ++r) {
            const int hr = h - PAD + r;
            float4 v;
            if (hr >= 0 && hr < Hn) {
                const float* xr = xb + ((size_t)c0 * Hn + hr) * Wn + w;
                v.x = xr[0 * Hn * Wn];
                v.y = xr[1 * Hn * Wn];
                v.z = xr[2 * Hn * Wn];
                v.w = xr[3 * Hn * Wn];
            } else {
                v = make_float4(0.f, 0.f, 0.f, 0.f);
            }
            *(float4*)(&xs[wv][r][w + PAD][0]) = v;
        }

        __syncthreads();  // order cross-lane LDS write->read (compiler fence)

        float acc[4][4] = {};  // [channel k][subpixel u]
        #pragma unroll
        for (int kh = 0; kh < Kk; ++kh) {
            #pragma unroll
            for (int kw = 0; kw < Kk; ++kw) {
                const float4 tap = *(const float4*)(&xs[wv][kh][w + kw][0]);
                const int t = kh * Kk + kw;
                #pragma unroll
                for (int u = 0; u < 4; ++u) {
                    const float wt = wreg[u * 25 + t];
                    acc[0][u] += tap.x * wt;
                    acc[1][u] += tap.y * wt;
                    acc[2][u] += tap.z * wt;
                    acc[3][u] += tap.w * wt;
                }
            }
        }

        __syncthreads();  // order LDS read -> next iteration's write

        // out[b, c0+k, 2h+i, 2w+j]; j pair contiguous -> float2 stores,
        // lane-consecutive -> 512B contiguous per wave store
        #pragma unroll
        for (int k = 0; k < 4; ++k) {
            #pragma unroll
            for (int i = 0; i < 2; ++i) {
                float2 o2 = make_float2(acc[k][2 * i + 0], acc[k][2 * i + 1]);
                *(float2*)(&ob[((size_t)(c0 + k) * (2 * Hn) + (2 * h + i)) *
                                   (2 * Wn) + 2 * w]) = o2;
            }
        }
    }
}

extern "C" void kernel_launch(void* const* d_in, const int* in_sizes, int n_in,
                              void* d_out, int out_size, void* d_ws, size_t ws_size,
                              hipStream_t stream)
{
    const float* x  = (const float*)d_in[0];
    const float* km = (const float*)d_in[1];
    float* out      = (float*)d_out;

    dim3 grid(Hn, Bn);
    carafe_fwd<<<grid, 256, 0, stream>>>(x, km, out);
}